// Round 6
// baseline (376.518 us; speedup 1.0000x reference)
//
#include <hip/hip_runtime.h>
#include <hip/hip_bf16.h>

// B=8192, N=M=K=2048, H=10.
// Pipeline (5 launches):
//   1) pre_kernel: col-sum partials + row sums of W + X -> 2-level int8 (X1,X2,sx1)
//   2) nca_update: finish col sums, per-cell MLP, write Wt = new_weight^T (fp32)
//   3) bquant: per-row 2-level int8 quantize of Wt -> B1,B2,sw1
//   4) i8 MFMA GEMM — ROUND 6 "split-pipe": the invariant across rounds 0-5 was
//      SQ_LDS_BANK_CONFLICT = 2^23 = exactly 4 cyc per ds_read_b128; LDS pipe
//      work (reads 55us + writes ~15us per-CU-normalized) EXCEEDS the 47us MFMA
//      floor -> LDS capacity-bound, schedule-invariant. Fix: B-fragments load
//      DIRECTLY from global (L2-resident: default XCD mapping pins same-bx
//      blocks to one XCD, 1MB B-slice/XCD), halving LDS reads and cutting
//      writes by 1/3. A stays LDS-staged (ring-3 x 16KB), asm ds_read;
//      B register-prefetched 1 tile ahead; exact-counted vmcnt FIFO, order
//      pinned with sched_barrier(0). 128x128 tile, 4 waves, 2 blocks/CU.
//   5) row softmax (one wave/row), applying sx1[row] on load.

typedef int int4v __attribute__((ext_vector_type(4)));
typedef int int16v __attribute__((ext_vector_type(16)));

#define GK 2048
#define NROWS 2048
#define MCOLS 2048
#define NCHUNK 16

// ---------------- fused pre-pass --------------------------------------------
#define CS_BLOCKS 128
#define RS_BLOCKS 2048
__global__ __launch_bounds__(256) void pre_kernel(
    const float* __restrict__ X, const float* __restrict__ W,
    signed char* __restrict__ X1, signed char* __restrict__ X2,
    float* __restrict__ sx1,
    float* __restrict__ part, float* __restrict__ rowS) {
  const int bid = blockIdx.x;
  const int tid = threadIdx.x;

  if (bid < CS_BLOCKS) {
    int chunk = bid >> 3;                 // 0..15
    int j = (bid & 7) * 256 + tid;        // column
    int i0 = chunk * (NROWS / NCHUNK);
    float s = 0.f;
    for (int i = i0; i < i0 + NROWS / NCHUNK; ++i) s += W[(size_t)i * MCOLS + j];
    part[(size_t)chunk * MCOLS + j] = s;
    return;
  }
  if (bid < CS_BLOCKS + RS_BLOCKS) {
    int row = bid - CS_BLOCKS;
    const float4* p = (const float4*)(W + (size_t)row * MCOLS);
    float4 a = p[tid];
    float4 b = p[tid + 256];
    float v = (a.x + a.y) + (a.z + a.w) + (b.x + b.y) + (b.z + b.w);
    __shared__ float red[256];
    red[tid] = v;
    __syncthreads();
    for (int s = 128; s > 0; s >>= 1) {
      if (tid < s) red[tid] += red[tid + s];
      __syncthreads();
    }
    if (tid == 0) rowS[row] = red[0];
    return;
  }
  // X row quantization: one block per row, 8 elems/thread
  {
    int row = bid - CS_BLOCKS - RS_BLOCKS;
    const float4* xr = (const float4*)(X + (size_t)row * GK);
    float4 a = xr[tid * 2];
    float4 b = xr[tid * 2 + 1];
    float xs[8] = {a.x, a.y, a.z, a.w, b.x, b.y, b.z, b.w};
    float am = 0.f;
#pragma unroll
    for (int i = 0; i < 8; ++i) am = fmaxf(am, fabsf(xs[i]));
    const int lane = tid & 63, wv = tid >> 6;
#pragma unroll
    for (int off = 32; off > 0; off >>= 1)
      am = fmaxf(am, __shfl_xor(am, off));
    __shared__ float wred[4];
    if (lane == 0) wred[wv] = am;
    __syncthreads();
    float amax = fmaxf(fmaxf(wred[0], wred[1]), fmaxf(wred[2], wred[3]));
    float s1 = amax * (1.0f / 127.0f);
    float inv = 127.0f / amax;
    int q1[8], q2[8];
#pragma unroll
    for (int i = 0; i < 8; ++i) {
      q1[i] = (int)rintf(xs[i] * inv);
      float r = xs[i] - (float)q1[i] * s1;
      q2[i] = (int)rintf(r * (254.0f * inv));
    }
    unsigned lo1 = (q1[0] & 255) | ((q1[1] & 255) << 8) | ((q1[2] & 255) << 16) | ((q1[3] & 255) << 24);
    unsigned hi1 = (q1[4] & 255) | ((q1[5] & 255) << 8) | ((q1[6] & 255) << 16) | ((q1[7] & 255) << 24);
    unsigned lo2 = (q2[0] & 255) | ((q2[1] & 255) << 8) | ((q2[2] & 255) << 16) | ((q2[3] & 255) << 24);
    unsigned hi2 = (q2[4] & 255) | ((q2[5] & 255) << 8) | ((q2[6] & 255) << 16) | ((q2[7] & 255) << 24);
    ((uint2*)(X1 + (size_t)row * GK))[tid] = make_uint2(lo1, hi1);
    ((uint2*)(X2 + (size_t)row * GK))[tid] = make_uint2(lo2, hi2);
    if (tid == 0) sx1[row] = s1;
  }
}

// ------- NCA MLP -> new_weight, transposed fp32 out -------------------------
__global__ __launch_bounds__(256) void nca_update_kernel(
    const float* __restrict__ W, const float* __restrict__ part,
    const float* __restrict__ rowS,
    const float* __restrict__ W1, const float* __restrict__ b1,
    const float* __restrict__ W2, const float* __restrict__ b2,
    const float* __restrict__ W3, const float* __restrict__ b3,
    float* __restrict__ Wt) {
  __shared__ float sColS[32];
  __shared__ float cred[NCHUNK][33];
  __shared__ float Tf[32][33];
  const int tid = threadIdx.x;
  const int i0 = blockIdx.y * 32;
  const int j0 = blockIdx.x * 32;

  {
    int ch = tid >> 5;
    int jl = tid & 31;
    cred[ch][jl]     = part[(size_t)ch * MCOLS + j0 + jl];
    cred[ch + 8][jl] = part[(size_t)(ch + 8) * MCOLS + j0 + jl];
  }
  __syncthreads();
  if (tid < 32) {
    float s = 0.f;
#pragma unroll
    for (int c = 0; c < NCHUNK; ++c) s += cred[c][tid];
    sColS[tid] = s;
  }
  __syncthreads();

  const int r = tid >> 5;
  const int c = tid & 31;

  float w[4], fwd[4], bwd[4];
#pragma unroll
  for (int cell = 0; cell < 4; ++cell) {
    int il = r + 8 * cell;
    float wv = W[(size_t)(i0 + il) * MCOLS + j0 + c];
    w[cell] = wv;
    fwd[cell] = (sColS[c] - wv) * (1.0f / (float)(NROWS - 1));
    bwd[cell] = (rowS[i0 + il] - wv) * (1.0f / (float)(MCOLS - 1));
  }

  float h1[4][10];
#pragma unroll
  for (int o = 0; o < 10; ++o) {
    float w1a = W1[o], w1b = W1[10 + o], w1c = W1[20 + o], bb = b1[o];
#pragma unroll
    for (int cell = 0; cell < 4; ++cell) {
      float v = fmaf(w[cell], w1a, fmaf(fwd[cell], w1b, fmaf(bwd[cell], w1c, bb)));
      h1[cell][o] = fmaxf(v, 0.f);
    }
  }
  const float b3v = b3[0];
  float u[4] = {b3v, b3v, b3v, b3v};
#pragma unroll
  for (int o = 0; o < 10; ++o) {
    float h2[4];
    float bb = b2[o];
#pragma unroll
    for (int cell = 0; cell < 4; ++cell) h2[cell] = bb;
#pragma unroll
    for (int p = 0; p < 10; ++p) {
      float wv = W2[p * 10 + o];
#pragma unroll
      for (int cell = 0; cell < 4; ++cell) h2[cell] = fmaf(h1[cell][p], wv, h2[cell]);
    }
    float w3 = W3[o];
#pragma unroll
    for (int cell = 0; cell < 4; ++cell) u[cell] = fmaf(fmaxf(h2[cell], 0.f), w3, u[cell]);
  }

#pragma unroll
  for (int cell = 0; cell < 4; ++cell) {
    int il = r + 8 * cell;
    Tf[il][c] = w[cell] + u[cell];
  }
  __syncthreads();

  {
    int r2 = tid >> 4;          // 0..15
    int ic = (tid & 15) * 2;    // 0..30
#pragma unroll
    for (int half = 0; half < 2; ++half) {
      int jl = r2 + 16 * half;
      float2 v = make_float2(Tf[ic][jl], Tf[ic + 1][jl]);
      *(float2*)(&Wt[(size_t)(j0 + jl) * NROWS + i0 + ic]) = v;
    }
  }
}

// -------- B quantize: one block per Wt row (= Wn column) --------------------
__global__ __launch_bounds__(256) void bquant_kernel(
    const float* __restrict__ Wt, signed char* __restrict__ B1,
    signed char* __restrict__ B2, float* __restrict__ sw1) {
  const int row = blockIdx.x;
  const int tid = threadIdx.x;
  const float4* wr = (const float4*)(Wt + (size_t)row * GK);
  float4 a = wr[tid * 2];
  float4 b = wr[tid * 2 + 1];
  float xs[8] = {a.x, a.y, a.z, a.w, b.x, b.y, b.z, b.w};
  float am = 0.f;
#pragma unroll
  for (int i = 0; i < 8; ++i) am = fmaxf(am, fabsf(xs[i]));
  const int lane = tid & 63, wv = tid >> 6;
#pragma unroll
  for (int off = 32; off > 0; off >>= 1)
    am = fmaxf(am, __shfl_xor(am, off));
  __shared__ float wred[4];
  if (lane == 0) wred[wv] = am;
  __syncthreads();
  float amax = fmaxf(fmaxf(wred[0], wred[1]), fmaxf(wred[2], wred[3]));
  float s1 = amax * (1.0f / 127.0f);
  float inv = 127.0f / amax;
  int q1[8], q2[8];
#pragma unroll
  for (int i = 0; i < 8; ++i) {
    q1[i] = (int)rintf(xs[i] * inv);
    float r = xs[i] - (float)q1[i] * s1;
    q2[i] = (int)rintf(r * (254.0f * inv));
  }
  unsigned lo1 = (q1[0] & 255) | ((q1[1] & 255) << 8) | ((q1[2] & 255) << 16) | ((q1[3] & 255) << 24);
  unsigned hi1 = (q1[4] & 255) | ((q1[5] & 255) << 8) | ((q1[6] & 255) << 16) | ((q1[7] & 255) << 24);
  unsigned lo2 = (q2[0] & 255) | ((q2[1] & 255) << 8) | ((q2[2] & 255) << 16) | ((q2[3] & 255) << 24);
  unsigned hi2 = (q2[4] & 255) | ((q2[5] & 255) << 8) | ((q2[6] & 255) << 16) | ((q2[7] & 255) << 24);
  ((uint2*)(B1 + (size_t)row * GK))[tid] = make_uint2(lo1, hi1);
  ((uint2*)(B2 + (size_t)row * GK))[tid] = make_uint2(lo2, hi2);
  if (tid == 0) sw1[row] = s1;
}

// ---------------- split-pipe 2-level i8 MFMA GEMM ---------------------------
// 128x128 tile, BK=64, 4 waves (2Mx2N, 64x64/wave).
// A (X1,X2) staged in LDS: ring of 3 x 16KB buffers (16 x 1KB blocks:
//   A1 blocks 0-7, A2 blocks 8-15). 1KB block = 16 rows x 64B; slot s holds
//   (row=s>>2, chunk=(s&3)^((s>>3)&3)); staging lane l fetches row l>>2,
//   chunk (l&3)^((l>>3)&3) (pre-swizzled global src, linear gload_lds dest).
//   Frag read (row rl, chunk c): slot = 4*rl + (c ^ ((rl>>1)&3)).
// B (B1q,B2q) NOT in LDS: fragments loaded straight from global/L2 via asm
//   global_load_dwordx4 (lane l: B[(n0+(l&31))*2048 + k + (l>>5)*16]),
//   register-prefetched 1 tile ahead (sets s0_/s1_ alternate).
// vmcnt FIFO per tile: [8 B(kt+1)][4 stageA(kt+2)] -> top wait vmcnt(12)
//   (drains stageA(kt)), pre-MFMA wait vmcnt(16) (drains B(kt)). Order pinned
//   with sched_barrier(0). Tail tiles use tightened counts.
#define BM 128
#define BN 128
#define BK 64
#define NT (GK / BK)
#define ABUF 16384

__device__ __forceinline__ void glds16(const signed char* g, char* l) {
  __builtin_amdgcn_global_load_lds(
      (const __attribute__((address_space(1))) void*)g,
      (__attribute__((address_space(3))) void*)l, 16, 0, 0);
}

__device__ __forceinline__ int4v ds_read128(const char* p) {
  int4v r;
  asm volatile("ds_read_b128 %0, %1"
               : "=v"(r)
               : "v"((const __attribute__((address_space(3))) char*)p));
  return r;
}

#define GLOAD(dst, vo, base, off)                                              \
  asm volatile("global_load_dwordx4 %0, %1, %2 offset:" off                    \
               : "=v"(dst) : "v"(vo), "s"(base))

#define MFMA_I8 __builtin_amdgcn_mfma_i32_32x32x32_i8

// 8 B-frag global loads for tile (vb pre-advanced to that tile's k0)
#define LOADB(NX)                                                              \
  GLOAD(NX##b1[0][0], vb0, B1g, "0");  GLOAD(NX##b1[0][1], vb0, B1g, "32");    \
  GLOAD(NX##b1[1][0], vb1, B1g, "0");  GLOAD(NX##b1[1][1], vb1, B1g, "32");    \
  GLOAD(NX##b2[0][0], vb0, B2g, "0");  GLOAD(NX##b2[0][1], vb0, B2g, "32");    \
  GLOAD(NX##b2[1][0], vb1, B2g, "0");  GLOAD(NX##b2[1][1], vb1, B2g, "32");    \
  vb0 += 64; vb1 += 64;

// 4 A-staging gloads (this wave's 4 x 1KB blocks), wave-uniform LDS dest
#define STAGEA(wb_, koff_)                                                     \
  glds16(gA0 + (koff_), (wb_) + swb0);                                         \
  glds16(gA1 + (koff_), (wb_) + swb1);                                         \
  glds16(gA2 + (koff_), (wb_) + swb2);                                         \
  glds16(gA3 + (koff_), (wb_) + swb3);

// 12 MFMAs for one ks; dependent writes to same acc spaced 4 apart
#define MM12(CUR, ks)                                                          \
  acc_h[0][0] = MFMA_I8(a1f[0][ks], CUR##b1[0][ks], acc_h[0][0], 0, 0, 0);     \
  acc_h[0][1] = MFMA_I8(a1f[0][ks], CUR##b1[1][ks], acc_h[0][1], 0, 0, 0);     \
  acc_h[1][0] = MFMA_I8(a1f[1][ks], CUR##b1[0][ks], acc_h[1][0], 0, 0, 0);     \
  acc_h[1][1] = MFMA_I8(a1f[1][ks], CUR##b1[1][ks], acc_h[1][1], 0, 0, 0);     \
  acc_c[0][0] = MFMA_I8(a1f[0][ks], CUR##b2[0][ks], acc_c[0][0], 0, 0, 0);     \
  acc_c[0][1] = MFMA_I8(a1f[0][ks], CUR##b2[1][ks], acc_c[0][1], 0, 0, 0);     \
  acc_c[1][0] = MFMA_I8(a1f[1][ks], CUR##b2[0][ks], acc_c[1][0], 0, 0, 0);     \
  acc_c[1][1] = MFMA_I8(a1f[1][ks], CUR##b2[1][ks], acc_c[1][1], 0, 0, 0);     \
  acc_c[0][0] = MFMA_I8(a2f[0][ks], CUR##b1[0][ks], acc_c[0][0], 0, 0, 0);     \
  acc_c[0][1] = MFMA_I8(a2f[0][ks], CUR##b1[1][ks], acc_c[0][1], 0, 0, 0);     \
  acc_c[1][0] = MFMA_I8(a2f[1][ks], CUR##b1[0][ks], acc_c[1][0], 0, 0, 0);     \
  acc_c[1][1] = MFMA_I8(a2f[1][ks], CUR##b1[1][ks], acc_c[1][1], 0, 0, 0);

// one pipeline step: top wait drains stageA(i); read A(i) frags; prefetch
// B(i+1) to NXT regs; stage A(i+2); pre-MFMA wait drains B(i); 24 MFMA on CUR.
#define STEP(i, CUR, NXT)                                                      \
  {                                                                            \
    if ((i) == NT - 1) asm volatile("s_waitcnt vmcnt(8)" ::: "memory");        \
    else               asm volatile("s_waitcnt vmcnt(12)" ::: "memory");       \
    __builtin_amdgcn_s_barrier();                                              \
    __builtin_amdgcn_sched_barrier(0);                                         \
    a1f[0][0] = ds_read128(rbuf + aoff[0][0]);                                 \
    a1f[0][1] = ds_read128(rbuf + aoff[0][1]);                                 \
    a1f[1][0] = ds_read128(rbuf + aoff[1][0]);                                 \
    a1f[1][1] = ds_read128(rbuf + aoff[1][1]);                                 \
    a2f[0][0] = ds_read128(rbuf + aoff[0][0] + 8192);                          \
    a2f[0][1] = ds_read128(rbuf + aoff[0][1] + 8192);                          \
    a2f[1][0] = ds_read128(rbuf + aoff[1][0] + 8192);                          \
    a2f[1][1] = ds_read128(rbuf + aoff[1][1] + 8192);                          \
    __builtin_amdgcn_sched_barrier(0);                                         \
    if ((i) + 1 < NT) { LOADB(NXT); }                                          \
    __builtin_amdgcn_sched_barrier(0);                                         \
    if ((i) + 2 < NT) { STAGEA(wbuf, (size_t)((i) + 2) * BK); }                \
    __builtin_amdgcn_sched_barrier(0);                                         \
    asm volatile("s_waitcnt lgkmcnt(0)" ::: "memory");                         \
    if ((i) < NT - 2)       asm volatile("s_waitcnt vmcnt(16)" ::: "memory");  \
    else if ((i) == NT - 2) asm volatile("s_waitcnt vmcnt(12)" ::: "memory");  \
    else                    asm volatile("s_waitcnt vmcnt(0)" ::: "memory");   \
    __builtin_amdgcn_sched_barrier(0);                                         \
    __builtin_amdgcn_s_setprio(1);                                             \
    MM12(CUR, 0);                                                              \
    MM12(CUR, 1);                                                              \
    __builtin_amdgcn_s_setprio(0);                                             \
    rbuf += ABUF; if (rbuf == sL + 3 * ABUF) rbuf = sL;                        \
    wbuf += ABUF; if (wbuf == sL + 3 * ABUF) wbuf = sL;                        \
  }

__global__ __launch_bounds__(256, 2) void gemm_kernel(
    const signed char* __restrict__ X1, const signed char* __restrict__ X2,
    const signed char* __restrict__ B1q, const signed char* __restrict__ B2q,
    const float* __restrict__ sw1, float* __restrict__ C) {
  __shared__ __align__(16) char sL[3 * ABUF];  // 48 KB

  const int tid = threadIdx.x;
  const int lane = tid & 63;
  const int wave = tid >> 6;   // 0..3
  const int wr = wave >> 1;    // 0..1 (M)
  const int wc = wave & 1;     // 0..1 (N)

  const int bx = blockIdx.x;   // 0..15
  const int by = blockIdx.y;   // 0..63

  const signed char* A1g = X1 + (size_t)(by * BM) * GK;
  const signed char* A2g = X2 + (size_t)(by * BM) * GK;
  const signed char* B1g = B1q + (size_t)(bx * BN) * GK;
  const signed char* B2g = B2q + (size_t)(bx * BN) * GK;

  // A staging: wave stages 1KB blocks wave*4..wave*4+3 (A1: 0-7, A2: 8-15)
  const int srow = lane >> 2;
  const int schk = (lane & 3) ^ ((lane >> 3) & 3);
  const int b0 = wave * 4;
  const signed char* gAbase = (b0 >= 8) ? A2g : A1g;
  const signed char* gA0 = gAbase + (size_t)(((b0 + 0) & 7) * 16 + srow) * GK + schk * 16;
  const signed char* gA1 = gAbase + (size_t)(((b0 + 1) & 7) * 16 + srow) * GK + schk * 16;
  const signed char* gA2 = gAbase + (size_t)(((b0 + 2) & 7) * 16 + srow) * GK + schk * 16;
  const signed char* gA3 = gAbase + (size_t)(((b0 + 3) & 7) * 16 + srow) * GK + schk * 16;
  const int swb0 = (b0 + 0) * 1024;
  const int swb1 = (b0 + 1) * 1024;
  const int swb2 = (b0 + 2) * 1024;
  const int swb3 = (b0 + 3) * 1024;

  // A frag read offsets (swizzled), within a 16KB buffer; A2 at +8192
  const int rl = lane & 15;
  const int fhalf = (lane >> 4) & 1;
  const int fck = lane >> 5;
  int aoff[2][2];
#pragma unroll
  for (int mi = 0; mi < 2; ++mi)
#pragma unroll
    for (int ks = 0; ks < 2; ++ks) {
      int c = 2 * ks + fck;
      int slot = 4 * rl + (c ^ ((rl >> 1) & 3));
      aoff[mi][ks] = (wr * 4 + mi * 2 + fhalf) * 1024 + slot * 16;
    }

  // B frag per-lane 32-bit offsets (rel. to B1g/B2g); ni=1 is +32*GK
  unsigned vb0 = (unsigned)((wc * 64 + (lane & 31)) * GK + ((lane >> 5) << 4));
  unsigned vb1 = vb0 + 32u * GK;

  int16v acc_h[2][2], acc_c[2][2];
#pragma unroll
  for (int i = 0; i < 2; ++i)
#pragma unroll
    for (int j = 0; j < 2; ++j)
#pragma unroll
      for (int e = 0; e < 16; ++e) { acc_h[i][j][e] = 0; acc_c[i][j][e] = 0; }

  int4v a1f[2][2], a2f[2][2];
  int4v s0_b1[2][2], s0_b2[2][2], s1_b1[2][2], s1_b2[2][2];

  const char* rbuf = sL;
  char* wbuf = sL + 2 * ABUF;

  // prologue — FIFO order matters: [stageA(0) 4][B(0) 8][stageA(1) 4]
  STAGEA(sL, 0);
  __builtin_amdgcn_sched_barrier(0);
  LOADB(s0_);
  __builtin_amdgcn_sched_barrier(0);
  STAGEA(sL + ABUF, BK);
  __builtin_amdgcn_sched_barrier(0);

#pragma unroll 1
  for (int i = 0; i < NT; i += 2) {
    STEP(i, s0_, s1_);
    STEP(i + 1, s1_, s0_);
  }

  // epilogue: C/D col=lane&31, row=(reg&3)+8*(reg>>2)+4*(lane>>5); apply sw1
  const int ecol = lane & 31;
  const int erow = 4 * (lane >> 5);
#pragma unroll
  for (int ni = 0; ni < 2; ++ni) {
    int col = bx * BN + wc * 64 + ni * 32 + ecol;
    float sw = sw1[col];
#pragma unroll
    for (int mi = 0; mi < 2; ++mi) {
#pragma unroll
      for (int reg = 0; reg < 16; ++reg) {
        int row = by * BM + wr * 64 + mi * 32 + (reg & 3) + 8 * (reg >> 2) + erow;
        float v = (float)acc_h[mi][ni][reg] + (float)acc_c[mi][ni][reg] * (1.0f / 254.0f);
        C[(size_t)row * MCOLS + col] = v * sw;
      }
    }
  }
}

// ---------------- row softmax: one wave per row, applies sx1[row] -----------
__global__ __launch_bounds__(256) void softmax_kernel(
    float* __restrict__ C, const float* __restrict__ sx1) {
  const int lane = threadIdx.x & 63;
  const int wv = threadIdx.x >> 6;
  const int row = blockIdx.x * 4 + wv;
  const float sx = sx1[row];
  float4* p = (float4*)(C + (size_t)row * MCOLS);

  float4 v[8];
#pragma unroll
  for (int j = 0; j < 8; ++j) {
    v[j] = p[j * 64 + lane];
    v[j].x *= sx; v[j].y *= sx; v[j].z *= sx; v[j].w *= sx;
  }

  float vmax = -3.4e38f;
#pragma unroll
  for (int j = 0; j < 8; ++j)
    vmax = fmaxf(vmax, fmaxf(fmaxf(v[j].x, v[j].y), fmaxf(v[j].z, v[j].w)));
#pragma unroll
  for (int off = 32; off > 0; off >>= 1)
    vmax = fmaxf(vmax, __shfl_xor(vmax, off));

  float sum = 0.f;
#pragma unroll
  for (int j = 0; j < 8; ++j) {
    v[j].x = __expf(v[j].x - vmax);
    v[j].y = __expf(v[j].y - vmax);
    v[j].z = __expf(v[j].z - vmax);
    v[j].w = __expf(v[j].w - vmax);
    sum += (v[j].x + v[j].y) + (v[j].z + v[j].w);
  }
#pragma unroll
  for (int off = 32; off > 0; off >>= 1)
    sum += __shfl_xor(sum, off);
  float inv = 1.0f / sum;

#pragma unroll
  for (int j = 0; j < 8; ++j) {
    v[j].x *= inv; v[j].y *= inv; v[j].z *= inv; v[j].w *= inv;
    p[j * 64 + lane] = v[j];
  }
}

// ---------------- launcher --------------------------------------------------
extern "C" void kernel_launch(void* const* d_in, const int* in_sizes, int n_in,
                              void* d_out, int out_size, void* d_ws, size_t ws_size,
                              hipStream_t stream) {
  const float* X      = (const float*)d_in[0];
  const float* weight = (const float*)d_in[1];
  const float* W1     = (const float*)d_in[2];
  const float* b1     = (const float*)d_in[3];
  const float* W2     = (const float*)d_in[4];
  const float* b2     = (const float*)d_in[5];
  const float* W3     = (const float*)d_in[6];
  const float* b3     = (const float*)d_in[7];
  float* out = (float*)d_out;

  const int N = 2048, M = 2048;
  const int Bdim = in_sizes[0] / N;   // 8192

  float* rowS = (float*)d_ws;
  float* part = rowS + 2048;
  float* sx1  = part + NCHUNK * 2048;
  float* sw1  = sx1 + 8192;
  float* Wt   = sw1 + 2048;
  signed char* X1 = (signed char*)(Wt + (size_t)M * N);
  signed char* X2 = X1 + (size_t)Bdim * N;
  signed char* B1q = X2 + (size_t)Bdim * N;
  signed char* B2q = B1q + (size_t)M * N;

  pre_kernel<<<CS_BLOCKS + RS_BLOCKS + Bdim, 256, 0, stream>>>(
      X, weight, X1, X2, sx1, part, rowS);

  nca_update_kernel<<<dim3(M / 32, N / 32), 256, 0, stream>>>(
      weight, part, rowS, W1, b1, W2, b2, W3, b3, Wt);

  bquant_kernel<<<M, 256, 0, stream>>>(Wt, B1q, B2q, sw1);

  gemm_kernel<<<dim3(M / BN, Bdim / BM), 256, 0, stream>>>(
      X1, X2, B1q, B2q, sw1, out);

  softmax_kernel<<<Bdim / 4, 256, 0, stream>>>(out, sx1);
}

// Round 7
// 325.580 us; speedup vs baseline: 1.1565x; 1.1565x over previous
//
#include <hip/hip_runtime.h>
#include <hip/hip_bf16.h>

// B=8192, N=M=K=2048, H=10.
// Pipeline (5 launches):
//   1) pre_kernel: col-sum partials + row sums of W + X -> 2-level int8 in
//      MFMA-FRAGMENT layout (X1f,X2f) + sx1 row scales. 4 rows/block, one
//      wave per row, thread t owns k-chunk t (32 vals) -> two 16B stores.
//   2) nca_update: finish col sums, per-cell MLP, write Wt = new_weight^T.
//   3) bquant: 4 rows/block 2-level int8 quantize of Wt -> B1f,B2f (fragment
//      layout) + sw1.
//   4) i8 MFMA GEMM — ROUND 7 "all-global frag-direct": NO LDS, NO barriers.
//      Fragment layout: frag(t32,k32) = 64 lanes x 16B contiguous (1KB);
//      every operand load is base+lane*16 = one coalesced dwordx4.
//      Evidence base: r6 halved LDS reads/conflicts exactly as modeled but
//      regressed on uncoalesced B loads (64 lines/instr); r0-r5 lockstep
//      schedules all ~117us. This kernel removes BOTH failure modes:
//      coalesced frag loads + free-running waves. Inputs (40MB) L3-resident.
//      512 thr (8 waves 4Mx2N, 64x64/wave), 2-deep reg pipeline (P/Q sets),
//      ~205 VGPR -> 2 waves/SIMD.
//   5) row softmax (one wave/row), applying sx1[row] on load.

typedef int int4v __attribute__((ext_vector_type(4)));
typedef int int16v __attribute__((ext_vector_type(16)));

#define GK 2048
#define NROWS 2048
#define MCOLS 2048
#define NCHUNK 16

// ---------------- fused pre-pass --------------------------------------------
#define CS_BLOCKS 128
#define RS_BLOCKS 2048
__global__ __launch_bounds__(256) void pre_kernel(
    const float* __restrict__ X, const float* __restrict__ W,
    signed char* __restrict__ X1, signed char* __restrict__ X2,
    float* __restrict__ sx1,
    float* __restrict__ part, float* __restrict__ rowS) {
  const int bid = blockIdx.x;
  const int tid = threadIdx.x;

  if (bid < CS_BLOCKS) {
    int chunk = bid >> 3;                 // 0..15
    int j = (bid & 7) * 256 + tid;        // column
    int i0 = chunk * (NROWS / NCHUNK);
    float s = 0.f;
    for (int i = i0; i < i0 + NROWS / NCHUNK; ++i) s += W[(size_t)i * MCOLS + j];
    part[(size_t)chunk * MCOLS + j] = s;
    return;
  }
  if (bid < CS_BLOCKS + RS_BLOCKS) {
    int row = bid - CS_BLOCKS;
    const float4* p = (const float4*)(W + (size_t)row * MCOLS);
    float4 a = p[tid];
    float4 b = p[tid + 256];
    float v = (a.x + a.y) + (a.z + a.w) + (b.x + b.y) + (b.z + b.w);
    __shared__ float red[256];
    red[tid] = v;
    __syncthreads();
    for (int s = 128; s > 0; s >>= 1) {
      if (tid < s) red[tid] += red[tid + s];
      __syncthreads();
    }
    if (tid == 0) rowS[row] = red[0];
    return;
  }
  // X quantization, FRAGMENT layout: 4 rows/block, wave wv -> row 4*rb+wv,
  // thread lane owns k-chunk = lane (32 values). Frag(m32,k32) lives at
  // int4v index ((m32*64 + k32)*64 + fraglane), fraglane = (row&31) + 32*hi.
  {
    int rb = bid - CS_BLOCKS - RS_BLOCKS;   // 0..2047
    const int lane = tid & 63, wv = tid >> 6;
    const int row = rb * 4 + wv;
    const float4* xr = (const float4*)(X + (size_t)row * GK) + lane * 8;
    float xs[32];
#pragma unroll
    for (int i = 0; i < 8; ++i) {
      float4 t = xr[i];
      xs[i * 4 + 0] = t.x; xs[i * 4 + 1] = t.y;
      xs[i * 4 + 2] = t.z; xs[i * 4 + 3] = t.w;
    }
    float am = 0.f;
#pragma unroll
    for (int i = 0; i < 32; ++i) am = fmaxf(am, fabsf(xs[i]));
#pragma unroll
    for (int off = 32; off > 0; off >>= 1)
      am = fmaxf(am, __shfl_xor(am, off));
    float s1 = am * (1.0f / 127.0f);
    float inv = 127.0f / am;
    unsigned w1[8], w2[8];
#pragma unroll
    for (int i = 0; i < 8; ++i) { w1[i] = 0u; w2[i] = 0u; }
#pragma unroll
    for (int i = 0; i < 32; ++i) {
      int q1 = (int)rintf(xs[i] * inv);
      float r = xs[i] - (float)q1 * s1;
      int q2 = (int)rintf(r * (254.0f * inv));
      w1[i >> 2] |= (unsigned)(q1 & 255) << ((i & 3) * 8);
      w2[i >> 2] |= (unsigned)(q2 & 255) << ((i & 3) * 8);
    }
    const int m32 = row >> 5, ml = row & 31;
    int4v* d1 = (int4v*)X1 + ((size_t)m32 * 64 + lane) * 64;
    int4v* d2 = (int4v*)X2 + ((size_t)m32 * 64 + lane) * 64;
    int4v v1lo = {(int)w1[0], (int)w1[1], (int)w1[2], (int)w1[3]};
    int4v v1hi = {(int)w1[4], (int)w1[5], (int)w1[6], (int)w1[7]};
    int4v v2lo = {(int)w2[0], (int)w2[1], (int)w2[2], (int)w2[3]};
    int4v v2hi = {(int)w2[4], (int)w2[5], (int)w2[6], (int)w2[7]};
    d1[ml]      = v1lo;
    d1[ml + 32] = v1hi;
    d2[ml]      = v2lo;
    d2[ml + 32] = v2hi;
    if (lane == 0) sx1[row] = s1;
  }
}

// ------- NCA MLP -> new_weight, transposed fp32 out -------------------------
__global__ __launch_bounds__(256) void nca_update_kernel(
    const float* __restrict__ W, const float* __restrict__ part,
    const float* __restrict__ rowS,
    const float* __restrict__ W1, const float* __restrict__ b1,
    const float* __restrict__ W2, const float* __restrict__ b2,
    const float* __restrict__ W3, const float* __restrict__ b3,
    float* __restrict__ Wt) {
  __shared__ float sColS[32];
  __shared__ float cred[NCHUNK][33];
  __shared__ float Tf[32][33];
  const int tid = threadIdx.x;
  const int i0 = blockIdx.y * 32;
  const int j0 = blockIdx.x * 32;

  {
    int ch = tid >> 5;
    int jl = tid & 31;
    cred[ch][jl]     = part[(size_t)ch * MCOLS + j0 + jl];
    cred[ch + 8][jl] = part[(size_t)(ch + 8) * MCOLS + j0 + jl];
  }
  __syncthreads();
  if (tid < 32) {
    float s = 0.f;
#pragma unroll
    for (int c = 0; c < NCHUNK; ++c) s += cred[c][tid];
    sColS[tid] = s;
  }
  __syncthreads();

  const int r = tid >> 5;
  const int c = tid & 31;

  float w[4], fwd[4], bwd[4];
#pragma unroll
  for (int cell = 0; cell < 4; ++cell) {
    int il = r + 8 * cell;
    float wv = W[(size_t)(i0 + il) * MCOLS + j0 + c];
    w[cell] = wv;
    fwd[cell] = (sColS[c] - wv) * (1.0f / (float)(NROWS - 1));
    bwd[cell] = (rowS[i0 + il] - wv) * (1.0f / (float)(MCOLS - 1));
  }

  float h1[4][10];
#pragma unroll
  for (int o = 0; o < 10; ++o) {
    float w1a = W1[o], w1b = W1[10 + o], w1c = W1[20 + o], bb = b1[o];
#pragma unroll
    for (int cell = 0; cell < 4; ++cell) {
      float v = fmaf(w[cell], w1a, fmaf(fwd[cell], w1b, fmaf(bwd[cell], w1c, bb)));
      h1[cell][o] = fmaxf(v, 0.f);
    }
  }
  const float b3v = b3[0];
  float u[4] = {b3v, b3v, b3v, b3v};
#pragma unroll
  for (int o = 0; o < 10; ++o) {
    float h2[4];
    float bb = b2[o];
#pragma unroll
    for (int cell = 0; cell < 4; ++cell) h2[cell] = bb;
#pragma unroll
    for (int p = 0; p < 10; ++p) {
      float wv = W2[p * 10 + o];
#pragma unroll
      for (int cell = 0; cell < 4; ++cell) h2[cell] = fmaf(h1[cell][p], wv, h2[cell]);
    }
    float w3 = W3[o];
#pragma unroll
    for (int cell = 0; cell < 4; ++cell) u[cell] = fmaf(fmaxf(h2[cell], 0.f), w3, u[cell]);
  }

#pragma unroll
  for (int cell = 0; cell < 4; ++cell) {
    int il = r + 8 * cell;
    Tf[il][c] = w[cell] + u[cell];
  }
  __syncthreads();

  {
    int r2 = tid >> 4;          // 0..15
    int ic = (tid & 15) * 2;    // 0..30
#pragma unroll
    for (int half = 0; half < 2; ++half) {
      int jl = r2 + 16 * half;
      float2 v = make_float2(Tf[ic][jl], Tf[ic + 1][jl]);
      *(float2*)(&Wt[(size_t)(j0 + jl) * NROWS + i0 + ic]) = v;
    }
  }
}

// -------- B quantize -> fragment layout: 4 Wt-rows per block ----------------
__global__ __launch_bounds__(256) void bquant_kernel(
    const float* __restrict__ Wt, signed char* __restrict__ B1,
    signed char* __restrict__ B2, float* __restrict__ sw1) {
  const int tid = threadIdx.x;
  const int lane = tid & 63, wv = tid >> 6;
  const int row = blockIdx.x * 4 + wv;    // Wt row = Wn column
  const float4* wr = (const float4*)(Wt + (size_t)row * GK) + lane * 8;
  float xs[32];
#pragma unroll
  for (int i = 0; i < 8; ++i) {
    float4 t = wr[i];
    xs[i * 4 + 0] = t.x; xs[i * 4 + 1] = t.y;
    xs[i * 4 + 2] = t.z; xs[i * 4 + 3] = t.w;
  }
  float am = 0.f;
#pragma unroll
  for (int i = 0; i < 32; ++i) am = fmaxf(am, fabsf(xs[i]));
#pragma unroll
  for (int off = 32; off > 0; off >>= 1)
    am = fmaxf(am, __shfl_xor(am, off));
  float s1 = am * (1.0f / 127.0f);
  float inv = 127.0f / am;
  unsigned w1[8], w2[8];
#pragma unroll
  for (int i = 0; i < 8; ++i) { w1[i] = 0u; w2[i] = 0u; }
#pragma unroll
  for (int i = 0; i < 32; ++i) {
    int q1 = (int)rintf(xs[i] * inv);
    float r = xs[i] - (float)q1 * s1;
    int q2 = (int)rintf(r * (254.0f * inv));
    w1[i >> 2] |= (unsigned)(q1 & 255) << ((i & 3) * 8);
    w2[i >> 2] |= (unsigned)(q2 & 255) << ((i & 3) * 8);
  }
  const int n32 = row >> 5, nl = row & 31;
  int4v* d1 = (int4v*)B1 + ((size_t)n32 * 64 + lane) * 64;
  int4v* d2 = (int4v*)B2 + ((size_t)n32 * 64 + lane) * 64;
  int4v v1lo = {(int)w1[0], (int)w1[1], (int)w1[2], (int)w1[3]};
  int4v v1hi = {(int)w1[4], (int)w1[5], (int)w1[6], (int)w1[7]};
  int4v v2lo = {(int)w2[0], (int)w2[1], (int)w2[2], (int)w2[3]};
  int4v v2hi = {(int)w2[4], (int)w2[5], (int)w2[6], (int)w2[7]};
  d1[nl]      = v1lo;
  d1[nl + 32] = v1hi;
  d2[nl]      = v2lo;
  d2[nl + 32] = v2hi;
  if (lane == 0) sw1[row] = s1;
}

// ---------------- all-global frag-direct 2-level i8 MFMA GEMM ---------------
// 256x128 tile, 8 waves (4Mx2N, 64x64/wave). NO LDS, NO barriers.
// Frag(t32,k32) stored contiguously: int4v idx = (t32*64 + k32)*64 + lane.
// Per k32 per wave: 8 coalesced dwordx4 loads (1KB each) + 12 MFMA.
// 2-deep register pipeline with static sets P/Q (rule #20).
#define BM 256
#define BN 128

#define MFMA_I8 __builtin_amdgcn_mfma_i32_32x32x32_i8

#define LOADT(S, k)                                                            \
  S##a1_0 = A1p[a0 + (size_t)(k) * 64];                                        \
  S##a1_1 = A1p[a1 + (size_t)(k) * 64];                                        \
  S##a2_0 = A2p[a0 + (size_t)(k) * 64];                                        \
  S##a2_1 = A2p[a1 + (size_t)(k) * 64];                                        \
  S##b1_0 = B1p[b0 + (size_t)(k) * 64];                                        \
  S##b1_1 = B1p[b1 + (size_t)(k) * 64];                                        \
  S##b2_0 = B2p[b0 + (size_t)(k) * 64];                                        \
  S##b2_1 = B2p[b1 + (size_t)(k) * 64];

#define MM12S(S)                                                               \
  acc_h[0][0] = MFMA_I8(S##a1_0, S##b1_0, acc_h[0][0], 0, 0, 0);               \
  acc_h[0][1] = MFMA_I8(S##a1_0, S##b1_1, acc_h[0][1], 0, 0, 0);               \
  acc_h[1][0] = MFMA_I8(S##a1_1, S##b1_0, acc_h[1][0], 0, 0, 0);               \
  acc_h[1][1] = MFMA_I8(S##a1_1, S##b1_1, acc_h[1][1], 0, 0, 0);               \
  acc_c[0][0] = MFMA_I8(S##a1_0, S##b2_0, acc_c[0][0], 0, 0, 0);               \
  acc_c[0][1] = MFMA_I8(S##a1_0, S##b2_1, acc_c[0][1], 0, 0, 0);               \
  acc_c[1][0] = MFMA_I8(S##a1_1, S##b2_0, acc_c[1][0], 0, 0, 0);               \
  acc_c[1][1] = MFMA_I8(S##a1_1, S##b2_1, acc_c[1][1], 0, 0, 0);               \
  acc_c[0][0] = MFMA_I8(S##a2_0, S##b1_0, acc_c[0][0], 0, 0, 0);               \
  acc_c[0][1] = MFMA_I8(S##a2_0, S##b1_1, acc_c[0][1], 0, 0, 0);               \
  acc_c[1][0] = MFMA_I8(S##a2_1, S##b1_0, acc_c[1][0], 0, 0, 0);               \
  acc_c[1][1] = MFMA_I8(S##a2_1, S##b1_1, acc_c[1][1], 0, 0, 0);

__global__ __launch_bounds__(512, 2) void gemm_kernel(
    const int4v* __restrict__ A1p, const int4v* __restrict__ A2p,
    const int4v* __restrict__ B1p, const int4v* __restrict__ B2p,
    const float* __restrict__ sw1, float* __restrict__ C) {
  const int tid = threadIdx.x;
  const int lane = tid & 63;
  const int wave = tid >> 6;   // 0..7
  const int wr = wave >> 1;    // 0..3 (M)
  const int wc = wave & 1;     // 0..1 (N)

  const int bx = blockIdx.x;   // 0..15
  const int by = blockIdx.y;   // 0..31

  // frag base indices (int4v units); advance by 64 per k32
  const size_t a0 = ((size_t)(by * 8 + wr * 2 + 0) * 64) * 64 + lane;
  const size_t a1 = ((size_t)(by * 8 + wr * 2 + 1) * 64) * 64 + lane;
  const size_t b0 = ((size_t)(bx * 4 + wc * 2 + 0) * 64) * 64 + lane;
  const size_t b1 = ((size_t)(bx * 4 + wc * 2 + 1) * 64) * 64 + lane;

  int16v acc_h[2][2], acc_c[2][2];
#pragma unroll
  for (int i = 0; i < 2; ++i)
#pragma unroll
    for (int j = 0; j < 2; ++j)
#pragma unroll
      for (int e = 0; e < 16; ++e) { acc_h[i][j][e] = 0; acc_c[i][j][e] = 0; }

  int4v Pa1_0, Pa1_1, Pa2_0, Pa2_1, Pb1_0, Pb1_1, Pb2_0, Pb2_1;
  int4v Qa1_0, Qa1_1, Qa2_0, Qa2_1, Qb1_0, Qb1_1, Qb2_0, Qb2_1;

  LOADT(P, 0);
#pragma unroll 1
  for (int k = 0; k < 62; k += 2) {
    LOADT(Q, k + 1);
    MM12S(P);
    LOADT(P, k + 2);
    MM12S(Q);
  }
  LOADT(Q, 63);
  MM12S(P);
  MM12S(Q);

  // epilogue: C/D col=lane&31, row=(reg&3)+8*(reg>>2)+4*(lane>>5); apply sw1
  const int ecol = lane & 31;
  const int erow = 4 * (lane >> 5);
#pragma unroll
  for (int ni = 0; ni < 2; ++ni) {
    int col = bx * BN + wc * 64 + ni * 32 + ecol;
    float sw = sw1[col];
#pragma unroll
    for (int mi = 0; mi < 2; ++mi) {
#pragma unroll
      for (int reg = 0; reg < 16; ++reg) {
        int row = by * BM + wr * 64 + mi * 32 + (reg & 3) + 8 * (reg >> 2) + erow;
        float v = (float)acc_h[mi][ni][reg] + (float)acc_c[mi][ni][reg] * (1.0f / 254.0f);
        C[(size_t)row * MCOLS + col] = v * sw;
      }
    }
  }
}

// ---------------- row softmax: one wave per row, applies sx1[row] -----------
__global__ __launch_bounds__(256) void softmax_kernel(
    float* __restrict__ C, const float* __restrict__ sx1) {
  const int lane = threadIdx.x & 63;
  const int wv = threadIdx.x >> 6;
  const int row = blockIdx.x * 4 + wv;
  const float sx = sx1[row];
  float4* p = (float4*)(C + (size_t)row * MCOLS);

  float4 v[8];
#pragma unroll
  for (int j = 0; j < 8; ++j) {
    v[j] = p[j * 64 + lane];
    v[j].x *= sx; v[j].y *= sx; v[j].z *= sx; v[j].w *= sx;
  }

  float vmax = -3.4e38f;
#pragma unroll
  for (int j = 0; j < 8; ++j)
    vmax = fmaxf(vmax, fmaxf(fmaxf(v[j].x, v[j].y), fmaxf(v[j].z, v[j].w)));
#pragma unroll
  for (int off = 32; off > 0; off >>= 1)
    vmax = fmaxf(vmax, __shfl_xor(vmax, off));

  float sum = 0.f;
#pragma unroll
  for (int j = 0; j < 8; ++j) {
    v[j].x = __expf(v[j].x - vmax);
    v[j].y = __expf(v[j].y - vmax);
    v[j].z = __expf(v[j].z - vmax);
    v[j].w = __expf(v[j].w - vmax);
    sum += (v[j].x + v[j].y) + (v[j].z + v[j].w);
  }
#pragma unroll
  for (int off = 32; off > 0; off >>= 1)
    sum += __shfl_xor(sum, off);
  float inv = 1.0f / sum;

#pragma unroll
  for (int j = 0; j < 8; ++j) {
    v[j].x *= inv; v[j].y *= inv; v[j].z *= inv; v[j].w *= inv;
    p[j * 64 + lane] = v[j];
  }
}

// ---------------- launcher --------------------------------------------------
extern "C" void kernel_launch(void* const* d_in, const int* in_sizes, int n_in,
                              void* d_out, int out_size, void* d_ws, size_t ws_size,
                              hipStream_t stream) {
  const float* X      = (const float*)d_in[0];
  const float* weight = (const float*)d_in[1];
  const float* W1     = (const float*)d_in[2];
  const float* b1     = (const float*)d_in[3];
  const float* W2     = (const float*)d_in[4];
  const float* b2     = (const float*)d_in[5];
  const float* W3     = (const float*)d_in[6];
  const float* b3     = (const float*)d_in[7];
  float* out = (float*)d_out;

  const int N = 2048, M = 2048;
  const int Bdim = in_sizes[0] / N;   // 8192

  float* rowS = (float*)d_ws;
  float* part = rowS + 2048;
  float* sx1  = part + NCHUNK * 2048;
  float* sw1  = sx1 + 8192;
  float* Wt   = sw1 + 2048;
  signed char* X1 = (signed char*)(Wt + (size_t)M * N);   // frag layout, 16MB
  signed char* X2 = X1 + (size_t)Bdim * N;                // frag layout, 16MB
  signed char* B1q = X2 + (size_t)Bdim * N;               // frag layout, 4MB
  signed char* B2q = B1q + (size_t)M * N;                 // frag layout, 4MB

  pre_kernel<<<CS_BLOCKS + RS_BLOCKS + Bdim / 4, 256, 0, stream>>>(
      X, weight, X1, X2, sx1, part, rowS);

  nca_update_kernel<<<dim3(M / 32, N / 32), 256, 0, stream>>>(
      weight, part, rowS, W1, b1, W2, b2, W3, b3, Wt);

  bquant_kernel<<<M / 4, 256, 0, stream>>>(Wt, B1q, B2q, sw1);

  gemm_kernel<<<dim3(M / BN, Bdim / BM), 512, 0, stream>>>(
      (const int4v*)X1, (const int4v*)X2, (const int4v*)B1q, (const int4v*)B2q,
      sw1, out);

  softmax_kernel<<<Bdim / 4, 256, 0, stream>>>(out, sx1);
}

// Round 8
// 303.765 us; speedup vs baseline: 1.2395x; 1.0718x over previous
//
#include <hip/hip_runtime.h>
#include <hip/hip_bf16.h>

// B=8192, N=M=K=2048, H=10.
// Pipeline (5 launches):
//   1) pre_kernel: col-sum partials + row sums of W + X -> 2-level int8 in
//      MFMA-FRAGMENT layout (X1f,X2f) + sx1. ROUND 8: LDS-bounce transpose so
//      the frag-layout stores are coalesced 64B lines (r7's scatter cost +27us).
//   2) nca_update: finish col sums, per-cell MLP, write Wt = new_weight^T.
//   3) bquant: 4 rows/block quantize of Wt -> B1f,B2f (frag layout, LDS-bounce
//      coalesced stores) + sw1.
//   4) i8 MFMA GEMM — all-global frag-direct (no LDS, no barriers) + ROUND 8:
//      sched_group_barrier interleave 8x{2 VMEM_READ, 3 MFMA} per iteration.
//      Evidence: r7 measured 126.8us = serialized model (L1 1024cyc + MFMA
//      877cyc per CU-step); overlapped model = 55us; MfmaUtil*dur == total
//      MFMA work in EVERY round -> pipes phase-alternate. Per-wave streams
//      were [8 loads][24 MFMA]; interleaving the stream co-feeds both pipes
//      even when waves are phase-locked.
//   5) row softmax (one wave/row), applying sx1[row] on load.

typedef int int4v __attribute__((ext_vector_type(4)));
typedef int int16v __attribute__((ext_vector_type(16)));

#define GK 2048
#define NROWS 2048
#define MCOLS 2048
#define NCHUNK 16

// ---------------- fused pre-pass --------------------------------------------
#define CS_BLOCKS 128
#define RS_BLOCKS 2048
__global__ __launch_bounds__(256) void pre_kernel(
    const float* __restrict__ X, const float* __restrict__ W,
    signed char* __restrict__ X1, signed char* __restrict__ X2,
    float* __restrict__ sx1,
    float* __restrict__ part, float* __restrict__ rowS) {
  const int bid = blockIdx.x;
  const int tid = threadIdx.x;

  if (bid < CS_BLOCKS) {
    int chunk = bid >> 3;                 // 0..15
    int j = (bid & 7) * 256 + tid;        // column
    int i0 = chunk * (NROWS / NCHUNK);
    float s = 0.f;
    for (int i = i0; i < i0 + NROWS / NCHUNK; ++i) s += W[(size_t)i * MCOLS + j];
    part[(size_t)chunk * MCOLS + j] = s;
    return;
  }
  if (bid < CS_BLOCKS + RS_BLOCKS) {
    int row = bid - CS_BLOCKS;
    const float4* p = (const float4*)(W + (size_t)row * MCOLS);
    float4 a = p[tid];
    float4 b = p[tid + 256];
    float v = (a.x + a.y) + (a.z + a.w) + (b.x + b.y) + (b.z + b.w);
    __shared__ float red[256];
    red[tid] = v;
    __syncthreads();
    for (int s = 128; s > 0; s >>= 1) {
      if (tid < s) red[tid] += red[tid + s];
      __syncthreads();
    }
    if (tid == 0) rowS[row] = red[0];
    return;
  }
  // X quantization -> fragment layout. 4 rows/block, wave wv = row 4*rb+wv,
  // lane owns k-chunk = lane (32 vals). Frag(m32,k32) = 64 int4v at
  // ((m32*64+k32)*64): [0..31]=lo rows, [32..63]=hi rows.
  // LDS bounce so global stores are 64B-coalesced.
  {
    int rb = bid - CS_BLOCKS - RS_BLOCKS;   // 0..2047
    const int lane = tid & 63, wv = tid >> 6;
    const int row = rb * 4 + wv;
    const float4* xr = (const float4*)(X + (size_t)row * GK) + lane * 8;
    float xs[32];
#pragma unroll
    for (int i = 0; i < 8; ++i) {
      float4 t = xr[i];
      xs[i * 4 + 0] = t.x; xs[i * 4 + 1] = t.y;
      xs[i * 4 + 2] = t.z; xs[i * 4 + 3] = t.w;
    }
    float am = 0.f;
#pragma unroll
    for (int i = 0; i < 32; ++i) am = fmaxf(am, fabsf(xs[i]));
#pragma unroll
    for (int off = 32; off > 0; off >>= 1)
      am = fmaxf(am, __shfl_xor(am, off));
    float s1 = am * (1.0f / 127.0f);
    float inv = 127.0f / am;
    unsigned w1[8], w2[8];
#pragma unroll
    for (int i = 0; i < 8; ++i) { w1[i] = 0u; w2[i] = 0u; }
#pragma unroll
    for (int i = 0; i < 32; ++i) {
      int q1 = (int)rintf(xs[i] * inv);
      float r = xs[i] - (float)q1 * s1;
      int q2 = (int)rintf(r * (254.0f * inv));
      w1[i >> 2] |= (unsigned)(q1 & 255) << ((i & 3) * 8);
      w2[i >> 2] |= (unsigned)(q2 & 255) << ((i & 3) * 8);
    }
    int4v v1lo = {(int)w1[0], (int)w1[1], (int)w1[2], (int)w1[3]};
    int4v v1hi = {(int)w1[4], (int)w1[5], (int)w1[6], (int)w1[7]};
    int4v v2lo = {(int)w2[0], (int)w2[1], (int)w2[2], (int)w2[3]};
    int4v v2hi = {(int)w2[4], (int)w2[5], (int)w2[6], (int)w2[7]};
    __shared__ int4v tr[4][2][2][65];   // [row][arr][lohi][k-chunk], padded
    tr[wv][0][0][lane] = v1lo;
    tr[wv][0][1][lane] = v1hi;
    tr[wv][1][0][lane] = v2lo;
    tr[wv][1][1][lane] = v2hi;
    if (lane == 0) sx1[row] = s1;
    __syncthreads();
    const int k = tid >> 2, r = tid & 3;
    const int m32 = rb >> 3;            // (rb*4)>>5
    const int ml0 = (rb * 4) & 31;
    int4v* d1 = (int4v*)X1 + ((size_t)m32 * 64 + k) * 64;
    int4v* d2 = (int4v*)X2 + ((size_t)m32 * 64 + k) * 64;
    d1[ml0 + r]      = tr[r][0][0][k];
    d1[ml0 + r + 32] = tr[r][0][1][k];
    d2[ml0 + r]      = tr[r][1][0][k];
    d2[ml0 + r + 32] = tr[r][1][1][k];
  }
}

// ------- NCA MLP -> new_weight, transposed fp32 out -------------------------
__global__ __launch_bounds__(256) void nca_update_kernel(
    const float* __restrict__ W, const float* __restrict__ part,
    const float* __restrict__ rowS,
    const float* __restrict__ W1, const float* __restrict__ b1,
    const float* __restrict__ W2, const float* __restrict__ b2,
    const float* __restrict__ W3, const float* __restrict__ b3,
    float* __restrict__ Wt) {
  __shared__ float sColS[32];
  __shared__ float cred[NCHUNK][33];
  __shared__ float Tf[32][33];
  const int tid = threadIdx.x;
  const int i0 = blockIdx.y * 32;
  const int j0 = blockIdx.x * 32;

  {
    int ch = tid >> 5;
    int jl = tid & 31;
    cred[ch][jl]     = part[(size_t)ch * MCOLS + j0 + jl];
    cred[ch + 8][jl] = part[(size_t)(ch + 8) * MCOLS + j0 + jl];
  }
  __syncthreads();
  if (tid < 32) {
    float s = 0.f;
#pragma unroll
    for (int c = 0; c < NCHUNK; ++c) s += cred[c][tid];
    sColS[tid] = s;
  }
  __syncthreads();

  const int r = tid >> 5;
  const int c = tid & 31;

  float w[4], fwd[4], bwd[4];
#pragma unroll
  for (int cell = 0; cell < 4; ++cell) {
    int il = r + 8 * cell;
    float wv = W[(size_t)(i0 + il) * MCOLS + j0 + c];
    w[cell] = wv;
    fwd[cell] = (sColS[c] - wv) * (1.0f / (float)(NROWS - 1));
    bwd[cell] = (rowS[i0 + il] - wv) * (1.0f / (float)(MCOLS - 1));
  }

  float h1[4][10];
#pragma unroll
  for (int o = 0; o < 10; ++o) {
    float w1a = W1[o], w1b = W1[10 + o], w1c = W1[20 + o], bb = b1[o];
#pragma unroll
    for (int cell = 0; cell < 4; ++cell) {
      float v = fmaf(w[cell], w1a, fmaf(fwd[cell], w1b, fmaf(bwd[cell], w1c, bb)));
      h1[cell][o] = fmaxf(v, 0.f);
    }
  }
  const float b3v = b3[0];
  float u[4] = {b3v, b3v, b3v, b3v};
#pragma unroll
  for (int o = 0; o < 10; ++o) {
    float h2[4];
    float bb = b2[o];
#pragma unroll
    for (int cell = 0; cell < 4; ++cell) h2[cell] = bb;
#pragma unroll
    for (int p = 0; p < 10; ++p) {
      float wv = W2[p * 10 + o];
#pragma unroll
      for (int cell = 0; cell < 4; ++cell) h2[cell] = fmaf(h1[cell][p], wv, h2[cell]);
    }
    float w3 = W3[o];
#pragma unroll
    for (int cell = 0; cell < 4; ++cell) u[cell] = fmaf(fmaxf(h2[cell], 0.f), w3, u[cell]);
  }

#pragma unroll
  for (int cell = 0; cell < 4; ++cell) {
    int il = r + 8 * cell;
    Tf[il][c] = w[cell] + u[cell];
  }
  __syncthreads();

  {
    int r2 = tid >> 4;          // 0..15
    int ic = (tid & 15) * 2;    // 0..30
#pragma unroll
    for (int half = 0; half < 2; ++half) {
      int jl = r2 + 16 * half;
      float2 v = make_float2(Tf[ic][jl], Tf[ic + 1][jl]);
      *(float2*)(&Wt[(size_t)(j0 + jl) * NROWS + i0 + ic]) = v;
    }
  }
}

// -------- B quantize -> fragment layout (LDS-bounce coalesced stores) -------
__global__ __launch_bounds__(256) void bquant_kernel(
    const float* __restrict__ Wt, signed char* __restrict__ B1,
    signed char* __restrict__ B2, float* __restrict__ sw1) {
  const int tid = threadIdx.x;
  const int lane = tid & 63, wv = tid >> 6;
  const int rb = blockIdx.x;              // 0..511
  const int row = rb * 4 + wv;            // Wt row = Wn column
  const float4* wr = (const float4*)(Wt + (size_t)row * GK) + lane * 8;
  float xs[32];
#pragma unroll
  for (int i = 0; i < 8; ++i) {
    float4 t = wr[i];
    xs[i * 4 + 0] = t.x; xs[i * 4 + 1] = t.y;
    xs[i * 4 + 2] = t.z; xs[i * 4 + 3] = t.w;
  }
  float am = 0.f;
#pragma unroll
  for (int i = 0; i < 32; ++i) am = fmaxf(am, fabsf(xs[i]));
#pragma unroll
  for (int off = 32; off > 0; off >>= 1)
    am = fmaxf(am, __shfl_xor(am, off));
  float s1 = am * (1.0f / 127.0f);
  float inv = 127.0f / am;
  unsigned w1[8], w2[8];
#pragma unroll
  for (int i = 0; i < 8; ++i) { w1[i] = 0u; w2[i] = 0u; }
#pragma unroll
  for (int i = 0; i < 32; ++i) {
    int q1 = (int)rintf(xs[i] * inv);
    float r = xs[i] - (float)q1 * s1;
    int q2 = (int)rintf(r * (254.0f * inv));
    w1[i >> 2] |= (unsigned)(q1 & 255) << ((i & 3) * 8);
    w2[i >> 2] |= (unsigned)(q2 & 255) << ((i & 3) * 8);
  }
  int4v v1lo = {(int)w1[0], (int)w1[1], (int)w1[2], (int)w1[3]};
  int4v v1hi = {(int)w1[4], (int)w1[5], (int)w1[6], (int)w1[7]};
  int4v v2lo = {(int)w2[0], (int)w2[1], (int)w2[2], (int)w2[3]};
  int4v v2hi = {(int)w2[4], (int)w2[5], (int)w2[6], (int)w2[7]};
  __shared__ int4v tr[4][2][2][65];
  tr[wv][0][0][lane] = v1lo;
  tr[wv][0][1][lane] = v1hi;
  tr[wv][1][0][lane] = v2lo;
  tr[wv][1][1][lane] = v2hi;
  if (lane == 0) sw1[row] = s1;
  __syncthreads();
  const int k = tid >> 2, r = tid & 3;
  const int n32 = rb >> 3;
  const int nl0 = (rb * 4) & 31;
  int4v* d1 = (int4v*)B1 + ((size_t)n32 * 64 + k) * 64;
  int4v* d2 = (int4v*)B2 + ((size_t)n32 * 64 + k) * 64;
  d1[nl0 + r]      = tr[r][0][0][k];
  d1[nl0 + r + 32] = tr[r][0][1][k];
  d2[nl0 + r]      = tr[r][1][0][k];
  d2[nl0 + r + 32] = tr[r][1][1][k];
}

// ---------------- all-global frag-direct 2-level i8 MFMA GEMM ---------------
// 256x128 tile, 8 waves (4Mx2N, 64x64/wave). NO LDS, NO barriers.
// Frag(t32,k32) contiguous: int4v idx = (t32*64 + k32)*64 + lane.
// 2-deep register pipeline (P/Q). sched_group_barrier forces per-iteration
// interleave 8x{2 VMEM_READ, 3 MFMA} so each wave co-feeds L1 and MFMA pipes.
#define BM 256
#define BN 128

#define MFMA_I8 __builtin_amdgcn_mfma_i32_32x32x32_i8

#define LOADT(S, k)                                                            \
  S##a1_0 = A1p[a0 + (size_t)(k) * 64];                                        \
  S##a1_1 = A1p[a1 + (size_t)(k) * 64];                                        \
  S##a2_0 = A2p[a0 + (size_t)(k) * 64];                                        \
  S##a2_1 = A2p[a1 + (size_t)(k) * 64];                                        \
  S##b1_0 = B1p[b0 + (size_t)(k) * 64];                                        \
  S##b1_1 = B1p[b1 + (size_t)(k) * 64];                                        \
  S##b2_0 = B2p[b0 + (size_t)(k) * 64];                                        \
  S##b2_1 = B2p[b1 + (size_t)(k) * 64];

#define MM12S(S)                                                               \
  acc_h[0][0] = MFMA_I8(S##a1_0, S##b1_0, acc_h[0][0], 0, 0, 0);               \
  acc_h[0][1] = MFMA_I8(S##a1_0, S##b1_1, acc_h[0][1], 0, 0, 0);               \
  acc_h[1][0] = MFMA_I8(S##a1_1, S##b1_0, acc_h[1][0], 0, 0, 0);               \
  acc_h[1][1] = MFMA_I8(S##a1_1, S##b1_1, acc_h[1][1], 0, 0, 0);               \
  acc_c[0][0] = MFMA_I8(S##a1_0, S##b2_0, acc_c[0][0], 0, 0, 0);               \
  acc_c[0][1] = MFMA_I8(S##a1_0, S##b2_1, acc_c[0][1], 0, 0, 0);               \
  acc_c[1][0] = MFMA_I8(S##a1_1, S##b2_0, acc_c[1][0], 0, 0, 0);               \
  acc_c[1][1] = MFMA_I8(S##a1_1, S##b2_1, acc_c[1][1], 0, 0, 0);               \
  acc_c[0][0] = MFMA_I8(S##a2_0, S##b1_0, acc_c[0][0], 0, 0, 0);               \
  acc_c[0][1] = MFMA_I8(S##a2_0, S##b1_1, acc_c[0][1], 0, 0, 0);               \
  acc_c[1][0] = MFMA_I8(S##a2_1, S##b1_0, acc_c[1][0], 0, 0, 0);               \
  acc_c[1][1] = MFMA_I8(S##a2_1, S##b1_1, acc_c[1][1], 0, 0, 0);

// one iteration handles 2 k-steps: 16 VMEM_READ + 24 MFMA = 8 x {2 VM, 3 MFMA}
#define SGB_PATTERN                                                            \
  _Pragma("unroll")                                                            \
  for (int _g = 0; _g < 8; ++_g) {                                             \
    __builtin_amdgcn_sched_group_barrier(0x020, 2, 0);  /* VMEM_READ */        \
    __builtin_amdgcn_sched_group_barrier(0x008, 3, 0);  /* MFMA      */        \
  }

__global__ __launch_bounds__(512, 2) void gemm_kernel(
    const int4v* __restrict__ A1p, const int4v* __restrict__ A2p,
    const int4v* __restrict__ B1p, const int4v* __restrict__ B2p,
    const float* __restrict__ sw1, float* __restrict__ C) {
  const int tid = threadIdx.x;
  const int lane = tid & 63;
  const int wave = tid >> 6;   // 0..7
  const int wr = wave >> 1;    // 0..3 (M)
  const int wc = wave & 1;     // 0..1 (N)

  const int bx = blockIdx.x;   // 0..15
  const int by = blockIdx.y;   // 0..31

  // frag base indices (int4v units); advance by 64 per k32
  const size_t a0 = ((size_t)(by * 8 + wr * 2 + 0) * 64) * 64 + lane;
  const size_t a1 = ((size_t)(by * 8 + wr * 2 + 1) * 64) * 64 + lane;
  const size_t b0 = ((size_t)(bx * 4 + wc * 2 + 0) * 64) * 64 + lane;
  const size_t b1 = ((size_t)(bx * 4 + wc * 2 + 1) * 64) * 64 + lane;

  int16v acc_h[2][2], acc_c[2][2];
#pragma unroll
  for (int i = 0; i < 2; ++i)
#pragma unroll
    for (int j = 0; j < 2; ++j)
#pragma unroll
      for (int e = 0; e < 16; ++e) { acc_h[i][j][e] = 0; acc_c[i][j][e] = 0; }

  int4v Pa1_0, Pa1_1, Pa2_0, Pa2_1, Pb1_0, Pb1_1, Pb2_0, Pb2_1;
  int4v Qa1_0, Qa1_1, Qa2_0, Qa2_1, Qb1_0, Qb1_1, Qb2_0, Qb2_1;

  LOADT(P, 0);
#pragma unroll 1
  for (int k = 0; k < 62; k += 2) {
    LOADT(Q, k + 1);
    MM12S(P);
    LOADT(P, k + 2);
    MM12S(Q);
    SGB_PATTERN;
  }
  LOADT(Q, 63);
  MM12S(P);
  MM12S(Q);

  // epilogue: C/D col=lane&31, row=(reg&3)+8*(reg>>2)+4*(lane>>5); apply sw1
  const int ecol = lane & 31;
  const int erow = 4 * (lane >> 5);
#pragma unroll
  for (int ni = 0; ni < 2; ++ni) {
    int col = bx * BN + wc * 64 + ni * 32 + ecol;
    float sw = sw1[col];
#pragma unroll
    for (int mi = 0; mi < 2; ++mi) {
#pragma unroll
      for (int reg = 0; reg < 16; ++reg) {
        int row = by * BM + wr * 64 + mi * 32 + (reg & 3) + 8 * (reg >> 2) + erow;
        float v = (float)acc_h[mi][ni][reg] + (float)acc_c[mi][ni][reg] * (1.0f / 254.0f);
        C[(size_t)row * MCOLS + col] = v * sw;
      }
    }
  }
}

// ---------------- row softmax: one wave per row, applies sx1[row] -----------
__global__ __launch_bounds__(256) void softmax_kernel(
    float* __restrict__ C, const float* __restrict__ sx1) {
  const int lane = threadIdx.x & 63;
  const int wv = threadIdx.x >> 6;
  const int row = blockIdx.x * 4 + wv;
  const float sx = sx1[row];
  float4* p = (float4*)(C + (size_t)row * MCOLS);

  float4 v[8];
#pragma unroll
  for (int j = 0; j < 8; ++j) {
    v[j] = p[j * 64 + lane];
    v[j].x *= sx; v[j].y *= sx; v[j].z *= sx; v[j].w *= sx;
  }

  float vmax = -3.4e38f;
#pragma unroll
  for (int j = 0; j < 8; ++j)
    vmax = fmaxf(vmax, fmaxf(fmaxf(v[j].x, v[j].y), fmaxf(v[j].z, v[j].w)));
#pragma unroll
  for (int off = 32; off > 0; off >>= 1)
    vmax = fmaxf(vmax, __shfl_xor(vmax, off));

  float sum = 0.f;
#pragma unroll
  for (int j = 0; j < 8; ++j) {
    v[j].x = __expf(v[j].x - vmax);
    v[j].y = __expf(v[j].y - vmax);
    v[j].z = __expf(v[j].z - vmax);
    v[j].w = __expf(v[j].w - vmax);
    sum += (v[j].x + v[j].y) + (v[j].z + v[j].w);
  }
#pragma unroll
  for (int off = 32; off > 0; off >>= 1)
    sum += __shfl_xor(sum, off);
  float inv = 1.0f / sum;

#pragma unroll
  for (int j = 0; j < 8; ++j) {
    v[j].x *= inv; v[j].y *= inv; v[j].z *= inv; v[j].w *= inv;
    p[j * 64 + lane] = v[j];
  }
}

// ---------------- launcher --------------------------------------------------
extern "C" void kernel_launch(void* const* d_in, const int* in_sizes, int n_in,
                              void* d_out, int out_size, void* d_ws, size_t ws_size,
                              hipStream_t stream) {
  const float* X      = (const float*)d_in[0];
  const float* weight = (const float*)d_in[1];
  const float* W1     = (const float*)d_in[2];
  const float* b1     = (const float*)d_in[3];
  const float* W2     = (const float*)d_in[4];
  const float* b2     = (const float*)d_in[5];
  const float* W3     = (const float*)d_in[6];
  const float* b3     = (const float*)d_in[7];
  float* out = (float*)d_out;

  const int N = 2048, M = 2048;
  const int Bdim = in_sizes[0] / N;   // 8192

  float* rowS = (float*)d_ws;
  float* part = rowS + 2048;
  float* sx1  = part + NCHUNK * 2048;
  float* sw1  = sx1 + 8192;
  float* Wt   = sw1 + 2048;
  signed char* X1 = (signed char*)(Wt + (size_t)M * N);   // frag layout, 16MB
  signed char* X2 = X1 + (size_t)Bdim * N;                // frag layout, 16MB
  signed char* B1q = X2 + (size_t)Bdim * N;               // frag layout, 4MB
  signed char* B2q = B1q + (size_t)M * N;                 // frag layout, 4MB

  pre_kernel<<<CS_BLOCKS + RS_BLOCKS + Bdim / 4, 256, 0, stream>>>(
      X, weight, X1, X2, sx1, part, rowS);

  nca_update_kernel<<<dim3(M / 32, N / 32), 256, 0, stream>>>(
      weight, part, rowS, W1, b1, W2, b2, W3, b3, Wt);

  bquant_kernel<<<M / 4, 256, 0, stream>>>(Wt, B1q, B2q, sw1);

  gemm_kernel<<<dim3(M / BN, Bdim / BM), 512, 0, stream>>>(
      (const int4v*)X1, (const int4v*)X2, (const int4v*)B1q, (const int4v*)B2q,
      sw1, out);

  softmax_kernel<<<Bdim / 4, 256, 0, stream>>>(out, sx1);
}